// Round 11
// baseline (207.789 us; speedup 1.0000x reference)
//
#include <hip/hip_runtime.h>
#include <hip/hip_bf16.h>
#include <stdint.h>

typedef __bf16 bf16_t;
typedef __bf16 bf16x8 __attribute__((ext_vector_type(8)));
typedef __bf16 bf16x4v __attribute__((ext_vector_type(4)));
typedef float f32x4 __attribute__((ext_vector_type(4)));
typedef float f32x16 __attribute__((ext_vector_type(16)));

#define DEV __device__ __forceinline__

static constexpr int B_ = 2, S_ = 4096, E_ = 768, H_ = 12, D_ = 64;
static constexpr int WINDOW_ = 128;
static constexpr float QSCALE = 0.125f * 1.44269504088896f;  // fold log2(e): softmax via exp2

template<int C> struct IC { static constexpr int v = C; };

// fast exp2: single v_exp_f32 (1-ulp; flushes large-negative to 0)
DEV float fexp2(float x) { return __builtin_amdgcn_exp2f(x); }

// pack 2 f32 -> dword of 2 bf16 (compiler fuses to v_cvt_pk_bf16_f32)
DEV uint32_t pk2(float lo, float hi) {
    union { bf16_t h[2]; uint32_t u; } r;
    r.h[0] = (bf16_t)lo; r.h[1] = (bf16_t)hi;
    return r.u;
}

// cross-half lane exchange: a_hi <-> b_lo (v_permlane32_swap_b32)
DEV void swap32(uint32_t& a, uint32_t& b) {
    auto r = __builtin_amdgcn_permlane32_swap(a, b, false, false);
    a = r[0]; b = r[1];
}

// ---------- async 16B global -> LDS ----------
DEV void gload_lds16(const void* g, void* l) {
    __builtin_amdgcn_global_load_lds(
        (const __attribute__((address_space(1))) uint32_t*)g,
        (__attribute__((address_space(3))) uint32_t*)l, 16, 0, 0);
}

// ---------- fp32 -> bf16 convert ----------
__global__ void k_cvt(const float* __restrict__ in, bf16_t* __restrict__ out, int n) {
    int i = (blockIdx.x * blockDim.x + threadIdx.x) * 4;
    if (i < n) {
        float4 v = *(const float4*)(in + i);
        bf16x4v o;
        o[0] = (bf16_t)v.x; o[1] = (bf16_t)v.y; o[2] = (bf16_t)v.z; o[3] = (bf16_t)v.w;
        *(bf16x4v*)(out + i) = o;
    }
}

// ---------- NT GEMM: C[m][n] = sum_k A[m][k] * Bw[n][k] + bias[n] ----------
// EPI 0: q (scaled, exp2-domain) / k into [B,H,S,D]; v into vt [B,H,D,S] (natural order)
// EPI 1: fp32 output [M][N]
template<int EPI>
__global__ void k_gemm(const bf16_t* __restrict__ A, const bf16_t* __restrict__ Bw,
                       const float* __restrict__ bias,
                       bf16_t* __restrict__ qb, bf16_t* __restrict__ kb, bf16_t* __restrict__ vtb,
                       float* __restrict__ outf,
                       int M, int N, int K, int mtiles) {
    __shared__ bf16_t As[128 * 64];
    __shared__ bf16_t Bs[128 * 64];
    int bid = blockIdx.x;
    int tm = bid % mtiles, tn = bid / mtiles;
    int m0 = tm * 128, n0 = tn * 128;
    int t = threadIdx.x;
    int lane = t & 63, wid = t >> 6;
    int l15 = lane & 15, l4 = lane >> 4;
    int wm = (wid & 1) * 64, wn = (wid >> 1) * 64;

    f32x4 acc[4][4];
#pragma unroll
    for (int i = 0; i < 4; ++i)
#pragma unroll
        for (int j = 0; j < 4; ++j) acc[i][j] = f32x4{0.f, 0.f, 0.f, 0.f};

    for (int kt = 0; kt < K; kt += 64) {
        __syncthreads();
#pragma unroll
        for (int c = 0; c < 4; ++c) {
            int idx = t + 256 * c;
            int row = idx >> 3, part = idx & 7;
            int kc = 8 * (part ^ (row & 7));
            gload_lds16(A + (long)(m0 + row) * K + kt + kc, (char*)As + idx * 16);
            gload_lds16(Bw + (long)(n0 + row) * K + kt + kc, (char*)Bs + idx * 16);
        }
        __syncthreads();
#pragma unroll
        for (int kk = 0; kk < 2; ++kk) {
            bf16x8 af[4], bfr[4];
#pragma unroll
            for (int i = 0; i < 4; ++i) {
                int row = wm + i * 16 + l15;
                int off = row * 128 + ((16 * (kk * 4 + l4)) ^ ((row & 7) << 4));
                af[i] = *(const bf16x8*)((const char*)As + off);
                int rowb = wn + i * 16 + l15;
                int offb = rowb * 128 + ((16 * (kk * 4 + l4)) ^ ((rowb & 7) << 4));
                bfr[i] = *(const bf16x8*)((const char*)Bs + offb);
            }
#pragma unroll
            for (int i = 0; i < 4; ++i)
#pragma unroll
                for (int j = 0; j < 4; ++j)
                    acc[i][j] = __builtin_amdgcn_mfma_f32_16x16x32_bf16(af[i], bfr[j], acc[i][j], 0, 0, 0);
        }
    }

#pragma unroll
    for (int i = 0; i < 4; ++i) {
#pragma unroll
        for (int j = 0; j < 4; ++j) {
            int n = n0 + wn + j * 16 + l15;
            float bv = bias[n];
            int mbase = m0 + wm + i * 16 + l4 * 4;
            if (EPI == 0) {
                int sel = n / 768, nn = n % 768;
                int h = nn >> 6, d = nn & 63;
                int b = mbase >> 12, s = mbase & 4095;
                if (sel == 2) {
                    bf16x4v pk;
#pragma unroll
                    for (int r = 0; r < 4; ++r) pk[r] = (bf16_t)(acc[i][j][r] + bv);
                    *(bf16x4v*)(vtb + ((long)(b * H_ + h) * D_ + d) * S_ + s) = pk;
                } else {
                    long o = ((long)(b * H_ + h) * S_ + s) * D_ + d;
#pragma unroll
                    for (int r = 0; r < 4; ++r) {
                        float v = acc[i][j][r] + bv;
                        if (sel == 0) qb[o + (long)r * D_] = (bf16_t)(v * QSCALE);
                        else          kb[o + (long)r * D_] = (bf16_t)v;
                    }
                }
            } else {
#pragma unroll
                for (int r = 0; r < 4; ++r)
                    outf[(long)(mbase + r) * 768 + n] = acc[i][j][r] + bv;
            }
        }
    }
}

// ---------- attention: 32x32x16 MFMA, 4 waves x 32 q, frozen-m, in-register P ----------
// QBLK=128, KVBLK=64, triple-buffered K/V, ONE barrier per tile.
__global__ __launch_bounds__(256, 3)
void k_attn(const bf16_t* __restrict__ q, const bf16_t* __restrict__ k,
            const bf16_t* __restrict__ vt, bf16_t* __restrict__ ao) {
    __shared__ bf16_t Ksh[3][4096];   // [key][d], 128B rows, 3-bit chunk XOR
    __shared__ bf16_t Vsh[3][4096];   // [d][key], 128B rows, 3-bit chunk XOR
    int bid = blockIdx.x;
    bid = (bid & 7) * 96 + (bid >> 3);    // XCD-aware swizzle (768 = 8*96)
    int bh = bid >> 5, qt = bid & 31;
    int q0 = qt * 128;
    int b = bh / H_, h = bh % H_;
    int t = threadIdx.x, lane = t & 63, wid = t >> 6;
    int l31 = lane & 31, l5 = lane >> 5;

    const bf16_t* qp = q + (long)bh * S_ * D_;
    const bf16_t* kp = k + (long)bh * S_ * D_;
    const bf16_t* vp = vt + (long)bh * D_ * S_;
    int wq = q0 + wid * 32;        // this wave's 32 q-rows
    int qg = wq + l31;             // this lane's q-row (D col)

    // Q B-fragments: col=q=l31, k-slot d = 16c + 8*l5 + e
    bf16x8 qf[4];
#pragma unroll
    for (int c = 0; c < 4; ++c)
        qf[c] = *(const bf16x8*)(qp + (long)qg * 64 + 16 * c + 8 * l5);

    // per-lane LDS fragment offsets (identical formula for K and V reads)
    int kofs[4];
#pragma unroll
    for (int c = 0; c < 4; ++c)
        kofs[c] = l31 * 128 + 16 * (((c << 1) + l5) ^ (lane & 7));

    f32x16 o0, o1, osum, mneg;
#pragma unroll
    for (int i = 0; i < 16; ++i) { o0[i] = 0.f; o1[i] = 0.f; osum[i] = 0.f; mneg[i] = 0.f; }

    bf16x8 onesA;
#pragma unroll
    for (int j = 0; j < 8; ++j) onesA[j] = (bf16_t)1.0f;

    // staging: 256 threads x (2 K-chunks + 2 V-chunks), linear LDS dest, pre-swizzled source
    int i2b = t + 256;
    int rowA = t >> 3, rowB = i2b >> 3;
    int koffA = rowA * 64 + 8 * ((t & 7) ^ (rowA & 7));
    int koffB = rowB * 64 + 8 * ((i2b & 7) ^ (rowB & 7));
    int voffA = rowA * S_ + 8 * ((t & 7) ^ (rowA & 7));
    int voffB = rowB * S_ + 8 * ((i2b & 7) ^ (rowB & 7));
    int qt2 = 2 * qt;

    auto NK = [&](int i) { return i < qt2 ? i : i + 2; };

    auto STAGE = [&](int kts, auto bufc) {
        constexpr int buf = decltype(bufc)::v;
        char* Kd = (char*)Ksh + buf * 8192 + t * 16;
        char* Vd = (char*)Vsh + buf * 8192 + t * 16;
        long ko = (long)kts << 12;
        int vo = kts << 6;
        gload_lds16(kp + ko + koffA, Kd);
        gload_lds16(kp + ko + koffB, Kd + 4096);
        gload_lds16(vp + vo + voffA, Vd);
        gload_lds16(vp + vo + voffB, Vd + 4096);
    };

    auto QKG = [&](const char* KL, const f32x16& ci) -> f32x16 {
        f32x16 s;
        bf16x8 kf = *(const bf16x8*)(KL + kofs[0]);
        s = __builtin_amdgcn_mfma_f32_32x32x16_bf16(kf, qf[0], ci, 0, 0, 0);
        kf = *(const bf16x8*)(KL + kofs[1]);
        s = __builtin_amdgcn_mfma_f32_32x32x16_bf16(kf, qf[1], s, 0, 0, 0);
        kf = *(const bf16x8*)(KL + kofs[2]);
        s = __builtin_amdgcn_mfma_f32_32x32x16_bf16(kf, qf[2], s, 0, 0, 0);
        kf = *(const bf16x8*)(KL + kofs[3]);
        s = __builtin_amdgcn_mfma_f32_32x32x16_bf16(kf, qf[3], s, 0, 0, 0);
        return s;
    };

    auto MASKG = [&](int kbase, f32x16& s) {
#pragma unroll
        for (int r = 0; r < 16; ++r) {
            int key = kbase + (r & 3) + 8 * (r >> 2);
            int dd = qg - key; int ad = dd < 0 ? -dd : dd;
            if (ad <= WINDOW_) s[r] = -1e30f;
        }
    };

    // exp + pack(P->B-frags via cvt_pk + permlane32_swap) + PV + rowsum
    auto SMTAIL = [&](f32x16& s, const char* VL, auto cbc) {
        constexpr int cb = decltype(cbc)::v;
#pragma unroll
        for (int r = 0; r < 16; ++r) s[r] = fexp2(s[r]);
#pragma unroll
        for (int cp = 0; cp < 2; ++cp) {
            uint32_t x  = pk2(s[8 * cp + 0], s[8 * cp + 1]);
            uint32_t y  = pk2(s[8 * cp + 2], s[8 * cp + 3]);
            uint32_t x2 = pk2(s[8 * cp + 4], s[8 * cp + 5]);
            uint32_t y2 = pk2(s[8 * cp + 6], s[8 * cp + 7]);
            swap32(x, x2);
            swap32(y, y2);
            union { uint32_t u[4]; bf16x8 v; } pb;
            pb.u[0] = x; pb.u[1] = y; pb.u[2] = x2; pb.u[3] = y2;
            bf16x8 va0 = *(const bf16x8*)(VL + kofs[cb + cp]);
            bf16x8 va1 = *(const bf16x8*)(VL + 4096 + kofs[cb + cp]);
            o0   = __builtin_amdgcn_mfma_f32_32x32x16_bf16(va0, pb.v, o0, 0, 0, 0);
            o1   = __builtin_amdgcn_mfma_f32_32x32x16_bf16(va1, pb.v, o1, 0, 0, 0);
            osum = __builtin_amdgcn_mfma_f32_32x32x16_bf16(onesA, pb.v, osum, 0, 0, 0);
        }
    };

    auto body = [&](int idx, auto curc) {
        constexpr int cur = decltype(curc)::v;
        if (idx < 61) {
            STAGE(NK(idx + 1), IC<(cur + 1) % 3>{});
            asm volatile("s_waitcnt vmcnt(4)" ::: "memory");   // tile idx landed
        } else {
            asm volatile("s_waitcnt vmcnt(0)" ::: "memory");
        }
        __builtin_amdgcn_s_barrier();
        __builtin_amdgcn_sched_barrier(0);

        int kt = NK(idx);
        int dk = kt - qt2;
        bool maskt = (dk == -2) | (dk == -1) | (dk == 2) | (dk == 3);
        const char* KL = (const char*)Ksh + cur * 8192;
        const char* VL = (const char*)Vsh + cur * 8192;

        f32x16 s = QKG(KL, mneg);                  // C-init = -m
        if (maskt) MASKG((kt << 6) + 4 * l5, s);
        SMTAIL(s, VL, IC<0>{});
        f32x16 s2 = QKG(KL + 4096, mneg);
        if (maskt) MASKG((kt << 6) + 32 + 4 * l5, s2);
        SMTAIL(s2, VL, IC<2>{});
    };

    STAGE(NK(0), IC<0>{});

    // ---- first tile: establish frozen m ----
    {
        STAGE(NK(1), IC<1>{});
        asm volatile("s_waitcnt vmcnt(4)" ::: "memory");
        __builtin_amdgcn_s_barrier();
        __builtin_amdgcn_sched_barrier(0);

        int kt = NK(0);
        int dk = kt - qt2;
        bool maskt = (dk == -2) | (dk == -1) | (dk == 2) | (dk == 3);
        const char* KL = (const char*)Ksh;
        const char* VL = (const char*)Vsh;

        f32x16 s = QKG(KL, mneg);                  // mneg == 0 here
        f32x16 s2 = QKG(KL + 4096, mneg);
        if (maskt) { MASKG((kt << 6) + 4 * l5, s); MASKG((kt << 6) + 32 + 4 * l5, s2); }

        float lm = s[0];
#pragma unroll
        for (int r = 1; r < 16; ++r) lm = fmaxf(lm, s[r]);
#pragma unroll
        for (int r = 0; r < 16; ++r) lm = fmaxf(lm, s2[r]);
        union { float f; uint32_t u; } ua, ub;
        ua.f = lm; ub.f = lm;
        swap32(ua.u, ub.u);
        lm = fmaxf(ua.f, ub.f);
        float m_ = fmaxf(lm, 0.0f);   // guard: rows fully masked in first tile
#pragma unroll
        for (int i = 0; i < 16; ++i) mneg[i] = -m_;
#pragma unroll
        for (int r = 0; r < 16; ++r) { s[r] -= m_; s2[r] -= m_; }
        SMTAIL(s, VL, IC<0>{});
        SMTAIL(s2, VL, IC<2>{});
    }

    for (int i3 = 0; i3 < 20; ++i3) {
        body(3 * i3 + 1, IC<1>{});
        body(3 * i3 + 2, IC<2>{});
        body(3 * i3 + 3, IC<0>{});
    }
    body(61, IC<1>{});

    // finalize + write [B,S,E] bf16 (osum col = this lane's q: plain scalar)
    float inv = 1.0f / osum[0];
    long baseo = ((long)b * S_ + qg) * E_ + h * 64;
#pragma unroll
    for (int dg = 0; dg < 2; ++dg) {
        const f32x16& oo = dg ? o1 : o0;
#pragma unroll
        for (int rq = 0; rq < 4; ++rq) {
            bf16x4v pk4;
#pragma unroll
            for (int j = 0; j < 4; ++j) pk4[j] = (bf16_t)(oo[rq * 4 + j] * inv);
            int d = 8 * rq + 4 * l5 + 32 * dg;
            *(bf16x4v*)(ao + baseo + d) = pk4;
        }
    }
}

extern "C" void kernel_launch(void* const* d_in, const int* in_sizes, int n_in,
                              void* d_out, int out_size, void* d_ws, size_t ws_size,
                              hipStream_t stream) {
    const float* x     = (const float*)d_in[0];
    const float* w_in  = (const float*)d_in[1];
    const float* b_in  = (const float*)d_in[2];
    const float* w_out = (const float*)d_in[3];
    const float* b_out = (const float*)d_in[4];
    float* out = (float*)d_out;

    char* ws = (char*)d_ws;
    bf16_t* xb  = (bf16_t*)(ws + 0);          // 12582912 (reused as attn-out)
    bf16_t* wib = (bf16_t*)(ws + 12582912);   // 3538944
    bf16_t* wob = (bf16_t*)(ws + 16121856);   // 1179648
    bf16_t* qb  = (bf16_t*)(ws + 17301504);   // 12582912
    bf16_t* kb  = (bf16_t*)(ws + 29884416);   // 12582912
    bf16_t* vtb = (bf16_t*)(ws + 42467328);   // 12582912
    bf16_t* ao  = xb;

    k_cvt<<<6144, 256, 0, stream>>>(x, xb, 6291456);
    k_cvt<<<1728, 256, 0, stream>>>(w_in, wib, 1769472);
    k_cvt<<<576, 256, 0, stream>>>(w_out, wob, 589824);

    // QKV projection: M=8192, N=2304, K=768 (v written pre-transposed, natural key order)
    k_gemm<0><<<64 * 18, 256, 0, stream>>>(xb, wib, b_in, qb, kb, vtb, nullptr,
                                           8192, 2304, 768, 64);
    k_attn<<<24 * 32, 256, 0, stream>>>(qb, kb, vtb, ao);
    // out projection: M=8192, N=768, K=768
    k_gemm<1><<<64 * 6, 256, 0, stream>>>(ao, wob, b_out, nullptr, nullptr, nullptr, out,
                                          8192, 768, 768, 64);
}

// Round 12
// 184.470 us; speedup vs baseline: 1.1264x; 1.1264x over previous
//
#include <hip/hip_runtime.h>
#include <hip/hip_bf16.h>
#include <stdint.h>

typedef __bf16 bf16_t;
typedef __bf16 bf16x8 __attribute__((ext_vector_type(8)));
typedef __bf16 bf16x4v __attribute__((ext_vector_type(4)));
typedef float f32x4 __attribute__((ext_vector_type(4)));

#define DEV __device__ __forceinline__

static constexpr int B_ = 2, S_ = 4096, E_ = 768, H_ = 12, D_ = 64;
static constexpr int WINDOW_ = 128;
static constexpr float QSCALE = 0.125f * 1.44269504088896f;  // fold log2(e): softmax via exp2

template<int C> struct IC { static constexpr int v = C; };

// fast exp2: single v_exp_f32 (1-ulp; flushes large-negative to 0)
DEV float fexp2(float x) { return __builtin_amdgcn_exp2f(x); }

// ---------- async 16B global -> LDS ----------
DEV void gload_lds16(const void* g, void* l) {
    __builtin_amdgcn_global_load_lds(
        (const __attribute__((address_space(1))) uint32_t*)g,
        (__attribute__((address_space(3))) uint32_t*)l, 16, 0, 0);
}

// ---------- fp32 -> bf16 convert ----------
__global__ void k_cvt(const float* __restrict__ in, bf16_t* __restrict__ out, int n) {
    int i = (blockIdx.x * blockDim.x + threadIdx.x) * 4;
    if (i < n) {
        float4 v = *(const float4*)(in + i);
        bf16x4v o;
        o[0] = (bf16_t)v.x; o[1] = (bf16_t)v.y; o[2] = (bf16_t)v.z; o[3] = (bf16_t)v.w;
        *(bf16x4v*)(out + i) = o;
    }
}

// ---------- NT GEMM: C[m][n] = sum_k A[m][k] * Bw[n][k] + bias[n] ----------
// EPI 0: q (scaled, exp2-domain) / k into [B,H,S,D]; v into vt [B,H,D,S] with keys
//        pre-permuted within 32-groups to match the PV A-fragment slot order.
// EPI 1: fp32 output [M][N]
template<int EPI>
__global__ void k_gemm(const bf16_t* __restrict__ A, const bf16_t* __restrict__ Bw,
                       const float* __restrict__ bias,
                       bf16_t* __restrict__ qb, bf16_t* __restrict__ kb, bf16_t* __restrict__ vtb,
                       float* __restrict__ outf,
                       int M, int N, int K, int mtiles) {
    __shared__ bf16_t As[128 * 64];
    __shared__ bf16_t Bs[128 * 64];
    int bid = blockIdx.x;
    int tm = bid % mtiles, tn = bid / mtiles;
    int m0 = tm * 128, n0 = tn * 128;
    int t = threadIdx.x;
    int lane = t & 63, wid = t >> 6;
    int l15 = lane & 15, l4 = lane >> 4;
    int wm = (wid & 1) * 64, wn = (wid >> 1) * 64;

    f32x4 acc[4][4];
#pragma unroll
    for (int i = 0; i < 4; ++i)
#pragma unroll
        for (int j = 0; j < 4; ++j) acc[i][j] = f32x4{0.f, 0.f, 0.f, 0.f};

    for (int kt = 0; kt < K; kt += 64) {
        __syncthreads();
#pragma unroll
        for (int c = 0; c < 4; ++c) {
            int idx = t + 256 * c;
            int row = idx >> 3, part = idx & 7;
            int kc = 8 * (part ^ (row & 7));
            gload_lds16(A + (long)(m0 + row) * K + kt + kc, (char*)As + idx * 16);
            gload_lds16(Bw + (long)(n0 + row) * K + kt + kc, (char*)Bs + idx * 16);
        }
        __syncthreads();
#pragma unroll
        for (int kk = 0; kk < 2; ++kk) {
            bf16x8 af[4], bfr[4];
#pragma unroll
            for (int i = 0; i < 4; ++i) {
                int row = wm + i * 16 + l15;
                int off = row * 128 + ((16 * (kk * 4 + l4)) ^ ((row & 7) << 4));
                af[i] = *(const bf16x8*)((const char*)As + off);
                int rowb = wn + i * 16 + l15;
                int offb = rowb * 128 + ((16 * (kk * 4 + l4)) ^ ((rowb & 7) << 4));
                bfr[i] = *(const bf16x8*)((const char*)Bs + offb);
            }
#pragma unroll
            for (int i = 0; i < 4; ++i)
#pragma unroll
                for (int j = 0; j < 4; ++j)
                    acc[i][j] = __builtin_amdgcn_mfma_f32_16x16x32_bf16(af[i], bfr[j], acc[i][j], 0, 0, 0);
        }
    }

#pragma unroll
    for (int i = 0; i < 4; ++i) {
#pragma unroll
        for (int j = 0; j < 4; ++j) {
            int n = n0 + wn + j * 16 + l15;
            float bv = bias[n];
            int mbase = m0 + wm + i * 16 + l4 * 4;
            if (EPI == 0) {
                int sel = n / 768, nn = n % 768;
                int h = nn >> 6, d = nn & 63;
                int b = mbase >> 12, s = mbase & 4095;
                if (sel == 2) {
                    bf16x4v pk;
#pragma unroll
                    for (int r = 0; r < 4; ++r) pk[r] = (bf16_t)(acc[i][j][r] + bv);
                    // permuted position: slot(8a+j)<-key(4a+j), slot(8a+4+j)<-key(16+4a+j)
                    int pos = (s & ~31) | (((s >> 2) & 3) << 3) | (((s >> 4) & 1) << 2);
                    *(bf16x4v*)(vtb + ((long)(b * H_ + h) * D_ + d) * S_ + pos) = pk;
                } else {
                    long o = ((long)(b * H_ + h) * S_ + s) * D_ + d;
#pragma unroll
                    for (int r = 0; r < 4; ++r) {
                        float v = acc[i][j][r] + bv;
                        if (sel == 0) qb[o + (long)r * D_] = (bf16_t)(v * QSCALE);
                        else          kb[o + (long)r * D_] = (bf16_t)v;
                    }
                }
            } else {
#pragma unroll
                for (int r = 0; r < 4; ++r)
                    outf[(long)(mbase + r) * 768 + n] = acc[i][j][r] + bv;
            }
        }
    }
}

// ---------- attention: swapped QK^T, frozen-m softmax, in-register P ----------
// 4 waves x 32 q (two 16-row halves sharing every K/V LDS read), KVBLK=64,
// triple-buffered K/V, ONE barrier per tile, -m folded into QK MFMA C-init.
__global__ __launch_bounds__(256, 3)
void k_attn(const bf16_t* __restrict__ q, const bf16_t* __restrict__ k,
            const bf16_t* __restrict__ vt, bf16_t* __restrict__ ao) {
    __shared__ bf16_t Ksh[3][4096];   // [key][d], 128B rows, 3-bit chunk XOR
    __shared__ bf16_t Vsh[3][4096];   // [d][pos], 128B rows, 3-bit chunk XOR
    int bid = blockIdx.x;
    bid = (bid & 7) * 96 + (bid >> 3);    // XCD-aware swizzle (768 = 8*96)
    int bh = bid >> 5, qt = bid & 31;
    int q0 = qt * 128;
    int b = bh / H_, h = bh % H_;
    int t = threadIdx.x, lane = t & 63, wid = t >> 6;
    int l15 = lane & 15, l4 = lane >> 4;

    const bf16_t* qp = q + (long)bh * S_ * D_;
    const bf16_t* kp = k + (long)bh * S_ * D_;
    const bf16_t* vp = vt + (long)bh * D_ * S_;
    int wq = q0 + wid * 32;              // this wave's 32 q-rows (2 halves of 16)

    // Q fragments per half (B-operand: col=q=l15, contraction d-chunk 8*l4)
    bf16x8 qf[2][2];
#pragma unroll
    for (int g = 0; g < 2; ++g) {
        int row = wq + g * 16 + l15;
        qf[g][0] = *(const bf16x8*)(qp + (long)row * 64 + 8 * l4);
        qf[g][1] = *(const bf16x8*)(qp + (long)row * 64 + 32 + 8 * l4);
    }

    // LDS fragment addressing: 2 VGPR bases + compile-time immediates
    int sw = (l15 & 7) << 4;
    int a0 = l15 * 128 + ((16 * l4) ^ sw);
    int a1 = a0 ^ 64;

    f32x4 o[2][4], osum[2];
    f32x4 mneg4[2];
#pragma unroll
    for (int g = 0; g < 2; ++g) {
        osum[g] = f32x4{0.f, 0.f, 0.f, 0.f};
        mneg4[g] = f32x4{0.f, 0.f, 0.f, 0.f};
#pragma unroll
        for (int ns = 0; ns < 4; ++ns) o[g][ns] = f32x4{0.f, 0.f, 0.f, 0.f};
    }

    bf16x8 onesB;
#pragma unroll
    for (int j = 0; j < 8; ++j) onesB[j] = (bf16_t)1.0f;

    // staging: 256 threads x (2 K-chunks + 2 V-chunks); linear LDS dest, pre-swizzled src
    int i2b = t + 256;
    int rowA = t >> 3, rowB = i2b >> 3;
    int part = t & 7;
    int koffA = rowA * 64 + 8 * (part ^ (rowA & 7));
    int koffB = rowB * 64 + 8 * (part ^ (rowB & 7));
    int voffA = rowA * S_ + 8 * (part ^ (rowA & 7));
    int voffB = rowB * S_ + 8 * (part ^ (rowB & 7));
    int qt2 = 2 * qt;
    int qg0 = wq + l15;       // g=0 q-row of this lane
    int qg1 = qg0 + 16;       // g=1

    auto NK = [&](int i) { return i < qt2 ? i : i + 2; };

    auto STAGE = [&](int kts, auto bufc) {
        constexpr int buf = decltype(bufc)::v;
        char* Kd = (char*)Ksh + buf * 8192 + t * 16;
        char* Vd = (char*)Vsh + buf * 8192 + t * 16;
        long ko = (long)kts << 12;
        int vo = kts << 6;
        gload_lds16(kp + ko + koffA, Kd);
        gload_lds16(kp + ko + koffB, Kd + 4096);
        gload_lds16(vp + vo + voffA, Vd);
        gload_lds16(vp + vo + voffB, Vd + 4096);
    };

    // QK for both halves, each K fragment read ONCE
    auto QK = [&](auto curc, f32x4 (*s)[4], f32x4 ci0, f32x4 ci1) {
        constexpr int cur = decltype(curc)::v;
        const char* KL = (const char*)Ksh + cur * 8192;
#pragma unroll
        for (int ks = 0; ks < 4; ++ks) {
            bf16x8 kf0 = *(const bf16x8*)(KL + a0 + ks * 2048);
            bf16x8 kf1 = *(const bf16x8*)(KL + a1 + ks * 2048);
            s[0][ks] = __builtin_amdgcn_mfma_f32_16x16x32_bf16(kf0, qf[0][0], ci0, 0, 0, 0);
            s[1][ks] = __builtin_amdgcn_mfma_f32_16x16x32_bf16(kf0, qf[1][0], ci1, 0, 0, 0);
            s[0][ks] = __builtin_amdgcn_mfma_f32_16x16x32_bf16(kf1, qf[0][1], s[0][ks], 0, 0, 0);
            s[1][ks] = __builtin_amdgcn_mfma_f32_16x16x32_bf16(kf1, qf[1][1], s[1][ks], 0, 0, 0);
        }
    };

    auto MASK = [&](int kt, f32x4 (*s)[4]) {
        int k0 = kt << 6;
#pragma unroll
        for (int ks = 0; ks < 4; ++ks) {
            int kb_ = k0 + ks * 16 + l4 * 4;
#pragma unroll
            for (int r = 0; r < 4; ++r) {
                int d0 = qg0 - (kb_ + r); int ad0 = d0 < 0 ? -d0 : d0;
                if (ad0 <= WINDOW_) s[0][ks][r] = -1e30f;
                int d1 = qg1 - (kb_ + r); int ad1 = d1 < 0 ? -d1 : d1;
                if (ad1 <= WINDOW_) s[1][ks][r] = -1e30f;
            }
        }
    };

    // pack P (both halves) + rowsum + PV with each V fragment read ONCE
    auto TAIL = [&](auto curc, f32x4 (*s)[4]) {
        constexpr int cur = decltype(curc)::v;
        bf16x8 pa[2][2];
#pragma unroll
        for (int g = 0; g < 2; ++g)
#pragma unroll
            for (int c = 0; c < 2; ++c) {
                pa[g][c][0] = (bf16_t)s[g][2*c][0];   pa[g][c][1] = (bf16_t)s[g][2*c][1];
                pa[g][c][2] = (bf16_t)s[g][2*c][2];   pa[g][c][3] = (bf16_t)s[g][2*c][3];
                pa[g][c][4] = (bf16_t)s[g][2*c+1][0]; pa[g][c][5] = (bf16_t)s[g][2*c+1][1];
                pa[g][c][6] = (bf16_t)s[g][2*c+1][2]; pa[g][c][7] = (bf16_t)s[g][2*c+1][3];
            }
#pragma unroll
        for (int g = 0; g < 2; ++g) {
            osum[g] = __builtin_amdgcn_mfma_f32_16x16x32_bf16(pa[g][0], onesB, osum[g], 0, 0, 0);
            osum[g] = __builtin_amdgcn_mfma_f32_16x16x32_bf16(pa[g][1], onesB, osum[g], 0, 0, 0);
        }
        const char* VL = (const char*)Vsh + cur * 8192;
#pragma unroll
        for (int ns = 0; ns < 4; ++ns) {
            bf16x8 vf0 = *(const bf16x8*)(VL + a0 + ns * 2048);
            bf16x8 vf1 = *(const bf16x8*)(VL + a1 + ns * 2048);
            o[0][ns] = __builtin_amdgcn_mfma_f32_16x16x32_bf16(pa[0][0], vf0, o[0][ns], 0, 0, 0);
            o[1][ns] = __builtin_amdgcn_mfma_f32_16x16x32_bf16(pa[1][0], vf0, o[1][ns], 0, 0, 0);
            o[0][ns] = __builtin_amdgcn_mfma_f32_16x16x32_bf16(pa[0][1], vf1, o[0][ns], 0, 0, 0);
            o[1][ns] = __builtin_amdgcn_mfma_f32_16x16x32_bf16(pa[1][1], vf1, o[1][ns], 0, 0, 0);
        }
    };

    auto body = [&](int idx, auto curc) {
        if (idx < 61) {
            STAGE(NK(idx + 1), IC<(decltype(curc)::v + 1) % 3>{});
            asm volatile("s_waitcnt vmcnt(4)" ::: "memory");  // tile idx landed
        } else {
            asm volatile("s_waitcnt vmcnt(0)" ::: "memory");
        }
        __builtin_amdgcn_s_barrier();
        __builtin_amdgcn_sched_barrier(0);

        int kt = NK(idx);
        int dk = kt - qt2;
        f32x4 s[2][4];
        QK(curc, s, mneg4[0], mneg4[1]);      // C-init = -m: MFMA emits s_raw - m
        if (dk == -2 || dk == -1 || dk == 2 || dk == 3) MASK(kt, s);
#pragma unroll
        for (int g = 0; g < 2; ++g)
#pragma unroll
            for (int ks = 0; ks < 4; ++ks)
#pragma unroll
                for (int r = 0; r < 4; ++r)
                    s[g][ks][r] = fexp2(s[g][ks][r]);
        TAIL(curc, s);
    };

    STAGE(NK(0), IC<0>{});

    // ---- first tile: establish frozen m (per half) ----
    {
        STAGE(NK(1), IC<1>{});
        asm volatile("s_waitcnt vmcnt(4)" ::: "memory");
        __builtin_amdgcn_s_barrier();
        __builtin_amdgcn_sched_barrier(0);

        int kt = NK(0);
        int dk = kt - qt2;
        f32x4 s[2][4];
        QK(IC<0>{}, s, f32x4{0.f,0.f,0.f,0.f}, f32x4{0.f,0.f,0.f,0.f});
        if (dk == -2 || dk == -1 || dk == 2 || dk == 3) MASK(kt, s);
#pragma unroll
        for (int g = 0; g < 2; ++g) {
            float lm = -1e30f;
#pragma unroll
            for (int ks = 0; ks < 4; ++ks) {
                float a = fmaxf(fmaxf(s[g][ks][0], s[g][ks][1]), fmaxf(s[g][ks][2], s[g][ks][3]));
                lm = fmaxf(lm, a);
            }
            lm = fmaxf(lm, __shfl_xor(lm, 16));
            lm = fmaxf(lm, __shfl_xor(lm, 32));
            float m_ = fmaxf(lm, 0.0f);   // guard: rows fully masked in first tile
            mneg4[g] = f32x4{-m_, -m_, -m_, -m_};
#pragma unroll
            for (int ks = 0; ks < 4; ++ks)
#pragma unroll
                for (int r = 0; r < 4; ++r)
                    s[g][ks][r] = fexp2(s[g][ks][r] - m_);
        }
        TAIL(IC<0>{}, s);
    }

    for (int i3 = 0; i3 < 20; ++i3) {
        body(3 * i3 + 1, IC<1>{});
        body(3 * i3 + 2, IC<2>{});
        body(3 * i3 + 3, IC<0>{});
    }
    body(61, IC<1>{});

    // finalize + write [B,S,E] bf16 (osum row-aligned with o)
#pragma unroll
    for (int g = 0; g < 2; ++g)
#pragma unroll
        for (int r = 0; r < 4; ++r) {
            float ir = 1.0f / osum[g][r];
            int srow2 = wq + g * 16 + l4 * 4 + r;
#pragma unroll
            for (int ns = 0; ns < 4; ++ns) {
                int e = h * 64 + ns * 16 + l15;
                ao[((long)b * S_ + srow2) * E_ + e] = (bf16_t)(o[g][ns][r] * ir);
            }
        }
}

extern "C" void kernel_launch(void* const* d_in, const int* in_sizes, int n_in,
                              void* d_out, int out_size, void* d_ws, size_t ws_size,
                              hipStream_t stream) {
    const float* x     = (const float*)d_in[0];
    const float* w_in  = (const float*)d_in[1];
    const float* b_in  = (const float*)d_in[2];
    const float* w_out = (const float*)d_in[3];
    const float* b_out = (const float*)d_in[4];
    float* out = (float*)d_out;

    char* ws = (char*)d_ws;
    bf16_t* xb  = (bf16_t*)(ws + 0);          // 12582912 (reused as attn-out)
    bf16_t* wib = (bf16_t*)(ws + 12582912);   // 3538944
    bf16_t* wob = (bf16_t*)(ws + 16121856);   // 1179648
    bf16_t* qb  = (bf16_t*)(ws + 17301504);   // 12582912
    bf16_t* kb  = (bf16_t*)(ws + 29884416);   // 12582912
    bf16_t* vtb = (bf16_t*)(ws + 42467328);   // 12582912
    bf16_t* ao  = xb;

    k_cvt<<<6144, 256, 0, stream>>>(x, xb, 6291456);
    k_cvt<<<1728, 256, 0, stream>>>(w_in, wib, 1769472);
    k_cvt<<<576, 256, 0, stream>>>(w_out, wob, 589824);

    // QKV projection: M=8192, N=2304, K=768 (v written pre-transposed + pre-permuted)
    k_gemm<0><<<64 * 18, 256, 0, stream>>>(xb, wib, b_in, qb, kb, vtb, nullptr,
                                           8192, 2304, 768, 64);
    k_attn<<<24 * 32, 256, 0, stream>>>(qb, kb, vtb, ao);
    // out projection: M=8192, N=768, K=768
    k_gemm<1><<<64 * 6, 256, 0, stream>>>(ao, wob, b_out, nullptr, nullptr, nullptr, out,
                                          8192, 768, 768, 64);
}